// Round 5
// baseline (188.365 us; speedup 1.0000x reference)
//
#include <hip/hip_runtime.h>
#include <hip/hip_bf16.h>
#include <cfloat>

#define V_ALL  6145      // 6144 words + 1 tail-target token
#define SPLIT_ 2048
#define NROW   128
#define DDIM   256
#define TEMP_  65.0f
#define KS     6160      // padded K row stride (multiple of 16)

// workspace layout in floats
#define EW_OFF 0
#define EW_SZ  (V_ALL * DDIM)          // 1,573,120 floats
#define HU_OFF (EW_OFF + EW_SZ)
#define HU_SZ  (NROW * DDIM)
#define RL_OFF (HU_OFF + HU_SZ)
#define RL_SZ  NROW
#define K_OFF  ((RL_OFF + RL_SZ + 3) & ~3)

// ---------------- kernel 1: hU[n][d] = sum_k h[n][k]*U[k][d] + b[d] ----------
__global__ __launch_bounds__(256) void k_hu(const float* __restrict__ h,
                                            const float* __restrict__ U,
                                            const float* __restrict__ b,
                                            float* __restrict__ hU) {
    const int d = threadIdx.x;
    const int n = blockIdx.x;
    const float4* __restrict__ hr = (const float4*)(h + n * DDIM); // uniform -> s_load
    float acc = b[d];
    #pragma unroll 8
    for (int k4 = 0; k4 < DDIM / 4; ++k4) {
        float4 hv = hr[k4];
        int k = k4 * 4;
        acc = fmaf(hv.x, U[(k + 0) * DDIM + d], acc);
        acc = fmaf(hv.y, U[(k + 1) * DDIM + d], acc);
        acc = fmaf(hv.z, U[(k + 2) * DDIM + d], acc);
        acc = fmaf(hv.w, U[(k + 3) * DDIM + d], acc);
    }
    hU[n * DDIM + d] = acc;
}

// ---------------- kernel 2: EW[v][d] = sum_k emb[v][k]*W[k][d] ---------------
// 8 vocab rows per block; emb reads are block-uniform (scalar loads), W reads
// coalesced across the 256 threads (d = tid).
__global__ __launch_bounds__(256) void k_ew(const float* __restrict__ emb,
                                            const float* __restrict__ W,
                                            float* __restrict__ EW) {
    const int d = threadIdx.x;
    const int v0 = blockIdx.x * 8;
    const float4* __restrict__ er[8];
    #pragma unroll
    for (int i = 0; i < 8; ++i) {
        int r = v0 + i;
        if (r > V_ALL - 1) r = V_ALL - 1;
        er[i] = (const float4*)(emb + r * DDIM);
    }
    float acc[8];
    #pragma unroll
    for (int i = 0; i < 8; ++i) acc[i] = 0.f;

    for (int k4 = 0; k4 < DDIM / 4; ++k4) {
        const int k = k4 * 4;
        const float w0 = W[(k + 0) * DDIM + d];
        const float w1 = W[(k + 1) * DDIM + d];
        const float w2 = W[(k + 2) * DDIM + d];
        const float w3 = W[(k + 3) * DDIM + d];
        #pragma unroll
        for (int i = 0; i < 8; ++i) {
            float4 e = er[i][k4];
            acc[i] = fmaf(e.x, w0, acc[i]);
            acc[i] = fmaf(e.y, w1, acc[i]);
            acc[i] = fmaf(e.z, w2, acc[i]);
            acc[i] = fmaf(e.w, w3, acc[i]);
        }
    }
    #pragma unroll
    for (int i = 0; i < 8; ++i) {
        int r = v0 + i;
        if (r <= V_ALL - 1) EW[r * DDIM + d] = acc[i];
    }
}

// ---------------- kernel 3: K[n][v] = 65/(1+dist(n,v)) -----------------------
// tile: 16 n-rows x 16 v-rows per block, 256 threads, one (n,v) per thread.
__device__ __forceinline__ float tanh_fast(float x) {
    // tanh(x) = 1 - 2/(exp(2x)+1); exp via native v_exp, rcp via v_rcp (~1ulp)
    float ex = __expf(2.f * x);
    return fmaf(-2.f, __builtin_amdgcn_rcpf(ex + 1.f), 1.f);
}

__global__ __launch_bounds__(256) void k_dist(const float* __restrict__ EW,
                                              const float* __restrict__ hU,
                                              const float* __restrict__ h,
                                              float* __restrict__ Km) {
    __shared__ float sEW[16][260];
    __shared__ float sHU[16][260];
    __shared__ float sH [16][260];

    const int v0 = blockIdx.x * 16;
    const int n0 = blockIdx.y * 16;

    #pragma unroll
    for (int j = 0; j < 4; ++j) {
        int idx = threadIdx.x + 256 * j;      // 0..1023
        int r   = idx >> 6;                   // 16 rows
        int c4  = idx & 63;                   // 64 float4 per row
        int vr  = v0 + r; if (vr > V_ALL - 1) vr = V_ALL - 1;
        *(float4*)&sEW[r][c4 * 4] = *(const float4*)&EW[vr * DDIM + c4 * 4];
        *(float4*)&sHU[r][c4 * 4] = *(const float4*)&hU[(n0 + r) * DDIM + c4 * 4];
        *(float4*)&sH [r][c4 * 4] = *(const float4*)&h [(n0 + r) * DDIM + c4 * 4];
    }
    __syncthreads();

    const int vl = threadIdx.x & 15;
    const int nl = threadIdx.x >> 4;
    const float* pe = &sEW[vl][0];
    const float* pa = &sHU[nl][0];
    const float* ph = &sH [nl][0];

    float acc = 0.f;
    #pragma unroll 4
    for (int d4 = 0; d4 < DDIM / 4; ++d4) {
        float4 e  = *(const float4*)(pe + d4 * 4);
        float4 a  = *(const float4*)(pa + d4 * 4);
        float4 hh = *(const float4*)(ph + d4 * 4);
        { float t = tanh_fast(e.x + a.x); float df = hh.x - t; acc = fmaf(df, df, acc); }
        { float t = tanh_fast(e.y + a.y); float df = hh.y - t; acc = fmaf(df, df, acc); }
        { float t = tanh_fast(e.z + a.z); float df = hh.z - t; acc = fmaf(df, df, acc); }
        { float t = tanh_fast(e.w + a.w); float df = hh.w - t; acc = fmaf(df, df, acc); }
    }
    float kk = TEMP_ / (1.f + acc);
    int vg = v0 + vl;
    if (vg <= V_ALL - 1) Km[(n0 + nl) * KS + vg] = kk;
}

// ---------------- kernel 4: per-row logsumexp (head + tail) + loss -----------
__device__ __forceinline__ float block_max(float x, volatile float* s4) {
    #pragma unroll
    for (int o = 32; o; o >>= 1) x = fmaxf(x, __shfl_down(x, o));
    __syncthreads();
    if ((threadIdx.x & 63) == 0) s4[threadIdx.x >> 6] = x;
    __syncthreads();
    return fmaxf(fmaxf(s4[0], s4[1]), fmaxf(s4[2], s4[3]));
}
__device__ __forceinline__ float block_sum(float x, volatile float* s4) {
    #pragma unroll
    for (int o = 32; o; o >>= 1) x += __shfl_down(x, o);
    __syncthreads();
    if ((threadIdx.x & 63) == 0) s4[threadIdx.x >> 6] = x;
    __syncthreads();
    return s4[0] + s4[1] + s4[2] + s4[3];
}

__global__ __launch_bounds__(256) void k_lse(const float* __restrict__ Km,
                                             const int* __restrict__ targets,
                                             float* __restrict__ rowloss) {
    __shared__ float s4[4];
    const int n = blockIdx.x;
    const int tid = threadIdx.x;
    const float* row = Km + n * KS;

    // head: cols 0..2047 plus col 6144 (the tail-target token)
    float m = -FLT_MAX;
    for (int v = tid; v < SPLIT_ + 1; v += 256) {
        int c = (v == SPLIT_) ? (V_ALL - 1) : v;
        m = fmaxf(m, row[c]);
    }
    float hmax = block_max(m, s4);
    float s = 0.f;
    for (int v = tid; v < SPLIT_ + 1; v += 256) {
        int c = (v == SPLIT_) ? (V_ALL - 1) : v;
        s += __expf(row[c] - hmax);
    }
    float hsum = block_sum(s, s4);

    // tail: cols 2048..6143
    m = -FLT_MAX;
    for (int v = tid; v < 4096; v += 256) m = fmaxf(m, row[SPLIT_ + v]);
    float tmax = block_max(m, s4);
    s = 0.f;
    for (int v = tid; v < 4096; v += 256) s += __expf(row[SPLIT_ + v] - tmax);
    float tsum = block_sum(s, s4);

    if (tid == 0) {
        float logZh = hmax + logf(hsum);
        float logZt = tmax + logf(tsum);
        int t = targets[n];
        float loss;
        if (t < SPLIT_) loss = logZh - row[t];
        else            loss = logZh + logZt - row[V_ALL - 1] - row[t];
        rowloss[n] = loss;
    }
}

// ---------------- kernel 5: mean over rows -----------------------------------
__global__ __launch_bounds__(128) void k_final(const float* __restrict__ rowloss,
                                               float* __restrict__ out) {
    const int tid = threadIdx.x;
    float x = rowloss[tid];
    #pragma unroll
    for (int o = 32; o; o >>= 1) x += __shfl_down(x, o);
    __shared__ float s[2];
    if ((tid & 63) == 0) s[tid >> 6] = x;
    __syncthreads();
    if (tid == 0) out[0] = (s[0] + s[1]) / (float)NROW;
}

extern "C" void kernel_launch(void* const* d_in, const int* in_sizes, int n_in,
                              void* d_out, int out_size, void* d_ws, size_t ws_size,
                              hipStream_t stream) {
    const float* h       = (const float*)d_in[0];
    const int*   targets = (const int*)  d_in[1];
    const float* emb     = (const float*)d_in[2];
    const float* W       = (const float*)d_in[3];
    const float* U       = (const float*)d_in[4];
    const float* b       = (const float*)d_in[5];

    float* ws = (float*)d_ws;
    float* EW = ws + EW_OFF;
    float* hU = ws + HU_OFF;
    float* rl = ws + RL_OFF;
    float* Km = ws + K_OFF;

    k_hu  <<<dim3(NROW),      dim3(256), 0, stream>>>(h, U, b, hU);
    k_ew  <<<dim3(769),       dim3(256), 0, stream>>>(emb, W, EW);      // ceil(6145/8)
    k_dist<<<dim3(385, 8),    dim3(256), 0, stream>>>(EW, hU, h, Km);   // ceil(6145/16) x 128/16
    k_lse <<<dim3(NROW),      dim3(256), 0, stream>>>(Km, targets, rl);
    k_final<<<dim3(1),        dim3(128), 0, stream>>>(rl, (float*)d_out);
}

// Round 13
// 181.516 us; speedup vs baseline: 1.0377x; 1.0377x over previous
//
#include <hip/hip_runtime.h>
#include <hip/hip_bf16.h>
#include <cfloat>

#define V_ALL  6145      // 6144 words + 1 tail-target token
#define NTOK   6144
#define SPLIT_ 2048
#define NROW   128
#define DDIM   256
#define TEMP_  65.0f
#define C2     2.8853900817779268f   // 2*log2(e): tanh(x) = 1 - 2/(2^(C2*x)+1)

// workspace layout in floats
#define EW_OFF 0
#define EW_SZ  (V_ALL * DDIM)          // 1,573,120 floats (pre-scaled by C2)
#define HU_OFF (EW_OFF + EW_SZ)
#define HU_SZ  (NROW * DDIM)           // pre-scaled by C2 (includes b)
#define HS_OFF (HU_OFF + HU_SZ)        // hsum[128]
#define TS_OFF (HS_OFF + NROW)         // tsum[128]
#define KT_OFF (TS_OFF + NROW)         // ktarget[128]
#define KL_OFF (KT_OFF + NROW)         // ktail[128]

// ---------------- kernel 1: hUs[n][d] = C2*(sum_k h[n][k]*U[k][d] + b[d]) ----
// also zeroes the hsum/tsum accumulators (runs before k_dist on the stream).
__global__ __launch_bounds__(256) void k_hu(const float* __restrict__ h,
                                            const float* __restrict__ U,
                                            const float* __restrict__ b,
                                            float* __restrict__ hUs,
                                            float* __restrict__ hsum,
                                            float* __restrict__ tsum) {
    const int d = threadIdx.x;
    const int n = blockIdx.x;
    if (d == 0) hsum[n] = 0.f;
    if (d == 1) tsum[n] = 0.f;
    const float4* __restrict__ hr = (const float4*)(h + n * DDIM); // uniform
    float acc = b[d];
    #pragma unroll 8
    for (int k4 = 0; k4 < DDIM / 4; ++k4) {
        float4 hv = hr[k4];
        int k = k4 * 4;
        acc = fmaf(hv.x, U[(k + 0) * DDIM + d], acc);
        acc = fmaf(hv.y, U[(k + 1) * DDIM + d], acc);
        acc = fmaf(hv.z, U[(k + 2) * DDIM + d], acc);
        acc = fmaf(hv.w, U[(k + 3) * DDIM + d], acc);
    }
    hUs[n * DDIM + d] = C2 * acc;
}

// ---------------- kernel 2: EWs[v][d] = C2 * sum_k emb[v][k]*W[k][d] ---------
__global__ __launch_bounds__(256) void k_ew(const float* __restrict__ emb,
                                            const float* __restrict__ W,
                                            float* __restrict__ EWs) {
    const int d = threadIdx.x;
    const int v0 = blockIdx.x * 8;
    const float4* __restrict__ er[8];
    #pragma unroll
    for (int i = 0; i < 8; ++i) {
        int r = v0 + i;
        if (r > V_ALL - 1) r = V_ALL - 1;
        er[i] = (const float4*)(emb + r * DDIM);
    }
    float acc[8];
    #pragma unroll
    for (int i = 0; i < 8; ++i) acc[i] = 0.f;

    for (int k4 = 0; k4 < DDIM / 4; ++k4) {
        const int k = k4 * 4;
        const float w0 = W[(k + 0) * DDIM + d];
        const float w1 = W[(k + 1) * DDIM + d];
        const float w2 = W[(k + 2) * DDIM + d];
        const float w3 = W[(k + 3) * DDIM + d];
        #pragma unroll
        for (int i = 0; i < 8; ++i) {
            float4 e = er[i][k4];
            acc[i] = fmaf(e.x, w0, acc[i]);
            acc[i] = fmaf(e.y, w1, acc[i]);
            acc[i] = fmaf(e.z, w2, acc[i]);
            acc[i] = fmaf(e.w, w3, acc[i]);
        }
    }
    #pragma unroll
    for (int i = 0; i < 8; ++i) {
        int r = v0 + i;
        if (r <= V_ALL - 1) EWs[r * DDIM + d] = C2 * acc[i];
    }
}

// ---------------- kernel 3: fused dist + kernel + online LSE -----------------
// tile 16n x 16v, one (n,v) per thread. k = 65/(1+dist) <= 65, so
// logZ = 65 + log(sum exp(k-65)) needs no max pass; partial sums reduced
// across the 16 v-lanes and atomically added to hsum/tsum per n-row.
__global__ __launch_bounds__(256) void k_dist(const float* __restrict__ EWs,
                                              const float* __restrict__ hUs,
                                              const float* __restrict__ h,
                                              const int* __restrict__ targets,
                                              float* __restrict__ hsum,
                                              float* __restrict__ tsum,
                                              float* __restrict__ ktarget,
                                              float* __restrict__ ktail) {
    __shared__ float sEW[16][260];
    __shared__ float sHU[16][260];
    __shared__ float sH [16][260];

    const int v0 = blockIdx.x * 16;
    const int n0 = blockIdx.y * 16;

    #pragma unroll
    for (int j = 0; j < 4; ++j) {
        int idx = threadIdx.x + 256 * j;      // 0..1023
        int r   = idx >> 6;                   // 16 rows
        int c4  = idx & 63;                   // 64 float4 per row
        int vr  = v0 + r; if (vr > V_ALL - 1) vr = V_ALL - 1;
        *(float4*)&sEW[r][c4 * 4] = *(const float4*)&EWs[vr * DDIM + c4 * 4];
        *(float4*)&sHU[r][c4 * 4] = *(const float4*)&hUs[(n0 + r) * DDIM + c4 * 4];
        *(float4*)&sH [r][c4 * 4] = *(const float4*)&h  [(n0 + r) * DDIM + c4 * 4];
    }
    __syncthreads();

    const int vl = threadIdx.x & 15;
    const int nl = threadIdx.x >> 4;
    const float* pe = &sEW[vl][0];
    const float* pa = &sHU[nl][0];
    const float* ph = &sH [nl][0];

    float acc0 = 0.f, acc1 = 0.f;
    #pragma unroll 4
    for (int d4 = 0; d4 < DDIM / 4; ++d4) {
        float4 e  = *(const float4*)(pe + d4 * 4);
        float4 a  = *(const float4*)(pa + d4 * 4);
        float4 hh = *(const float4*)(ph + d4 * 4);
        // arg already scaled by C2 = 2*log2(e): tanh = 1 - 2*rcp(2^arg + 1)
        { float ex = __builtin_amdgcn_exp2f(e.x + a.x);
          float t  = fmaf(-2.f, __builtin_amdgcn_rcpf(ex + 1.f), 1.f);
          float df = hh.x - t; acc0 = fmaf(df, df, acc0); }
        { float ex = __builtin_amdgcn_exp2f(e.y + a.y);
          float t  = fmaf(-2.f, __builtin_amdgcn_rcpf(ex + 1.f), 1.f);
          float df = hh.y - t; acc1 = fmaf(df, df, acc1); }
        { float ex = __builtin_amdgcn_exp2f(e.z + a.z);
          float t  = fmaf(-2.f, __builtin_amdgcn_rcpf(ex + 1.f), 1.f);
          float df = hh.z - t; acc0 = fmaf(df, df, acc0); }
        { float ex = __builtin_amdgcn_exp2f(e.w + a.w);
          float t  = fmaf(-2.f, __builtin_amdgcn_rcpf(ex + 1.f), 1.f);
          float df = hh.w - t; acc1 = fmaf(df, df, acc1); }
    }
    const float kk = TEMP_ / (1.f + acc0 + acc1);

    const int vg = v0 + vl;
    const int n  = n0 + nl;
    const bool valid = (vg <= NTOK);
    float ek = valid ? __expf(kk - 65.f) : 0.f;   // in [e^-65, 1], no under/overflow

    // butterfly sum across the 16 v-lanes (in-wave, width 16)
    ek += __shfl_xor(ek, 1, 16);
    ek += __shfl_xor(ek, 2, 16);
    ek += __shfl_xor(ek, 4, 16);
    ek += __shfl_xor(ek, 8, 16);

    // region is block-uniform: boundaries 2048/6144 are multiples of 16;
    // block v0==6144 holds only the tail-target token, which belongs to head.
    const bool is_head = (v0 < SPLIT_) || (v0 >= NTOK);
    if (vl == 0) {
        float* dst = is_head ? hsum : tsum;
        atomicAdd(&dst[n], ek);
    }
    if (valid) {
        int tn = targets[n];
        if (vg == tn)   ktarget[n] = kk;
        if (vg == NTOK) ktail[n]   = kk;
    }
}

// ---------------- kernel 4: per-row loss + mean ------------------------------
__global__ __launch_bounds__(128) void k_loss(const float* __restrict__ hsum,
                                              const float* __restrict__ tsum,
                                              const float* __restrict__ ktarget,
                                              const float* __restrict__ ktail,
                                              const int* __restrict__ targets,
                                              float* __restrict__ out) {
    const int n = threadIdx.x;
    const float logZh = 65.f + logf(hsum[n]);
    const int t = targets[n];
    float loss;
    if (t < SPLIT_) loss = logZh - ktarget[n];
    else            loss = logZh + 65.f + logf(tsum[n]) - ktail[n] - ktarget[n];

    #pragma unroll
    for (int o = 32; o; o >>= 1) loss += __shfl_down(loss, o);
    __shared__ float s[2];
    if ((n & 63) == 0) s[n >> 6] = loss;
    __syncthreads();
    if (n == 0) out[0] = (s[0] + s[1]) / (float)NROW;
}

extern "C" void kernel_launch(void* const* d_in, const int* in_sizes, int n_in,
                              void* d_out, int out_size, void* d_ws, size_t ws_size,
                              hipStream_t stream) {
    const float* h       = (const float*)d_in[0];
    const int*   targets = (const int*)  d_in[1];
    const float* emb     = (const float*)d_in[2];
    const float* W       = (const float*)d_in[3];
    const float* U       = (const float*)d_in[4];
    const float* b       = (const float*)d_in[5];

    float* ws  = (float*)d_ws;
    float* EWs = ws + EW_OFF;
    float* hUs = ws + HU_OFF;
    float* hs  = ws + HS_OFF;
    float* ts  = ws + TS_OFF;
    float* kt  = ws + KT_OFF;
    float* kl  = ws + KL_OFF;

    k_hu  <<<dim3(NROW),   dim3(256), 0, stream>>>(h, U, b, hUs, hs, ts);
    k_ew  <<<dim3(769),    dim3(256), 0, stream>>>(emb, W, EWs);           // ceil(6145/8)
    k_dist<<<dim3(385, 8), dim3(256), 0, stream>>>(EWs, hUs, h, targets,
                                                   hs, ts, kt, kl);        // ceil(6145/16) x 8
    k_loss<<<dim3(1),      dim3(128), 0, stream>>>(hs, ts, kt, kl, targets,
                                                   (float*)d_out);
}